// Round 10
// baseline (2818.358 us; speedup 1.0000x reference)
//
#include <hip/hip_runtime.h>

typedef unsigned long long ull;

#define N0_ 100000
#define N1_ 50000
#define N2_ 25000
#define N3_ 12500
#define EDG 1600000
#define CAP1 600000
#define CAP2 200000
#define CAP3 80000
#define RB 65536

struct Sel { ull prefix; int remaining; };

// ---- ticket: returns true in exactly one (the last-finishing) block. ----
// All threads call it; all threads of the last block return true.
__device__ __forceinline__ bool ticket_last(int* tick) {
  __shared__ int lastf;
  __threadfence();
  __syncthreads();
  if (threadIdx.x == 0)
    lastf = (atomicAdd(tick, 1) == (int)gridDim.x - 1) ? 1 : 0;
  __syncthreads();
  if (lastf) __threadfence();
  return lastf != 0;
}

// ---------------- kernels ----------------

__global__ void sentinel_k(float* o, float v) { if (threadIdx.x == 0) o[0] = v; }

// C[n,128] = A[n,128] @ W[128,128] (+bias), ACC-typed accumulate. 64 rows/block.
template <typename TA, typename TC, typename ACC>
__global__ __launch_bounds__(256) void matmul128(const TA* __restrict__ A,
    const float* __restrict__ W, const float* __restrict__ bias,
    TC* __restrict__ C, int n) {
  __shared__ float Al[64 * 33];
  __shared__ float Wl[32 * 128];
  int tid = threadIdx.x;
  int colb = tid & 31;
  int rg = tid >> 5;
  int row0 = blockIdx.x * 64;
  ACC acc[8][4];
#pragma unroll
  for (int r = 0; r < 8; ++r)
#pragma unroll
    for (int j = 0; j < 4; ++j) acc[r][j] = (ACC)0;
  for (int kt = 0; kt < 128; kt += 32) {
    for (int i = tid; i < 64 * 32; i += 256) {
      int r = i >> 5, kk = i & 31;
      int row = row0 + r;
      Al[r * 33 + kk] = (row < n) ? (float)A[(size_t)row * 128 + kt + kk] : 0.0f;
    }
    for (int i = tid; i < 32 * 128; i += 256) {
      int kk = i >> 7, c = i & 127;
      Wl[i] = W[(size_t)(kt + kk) * 128 + c];
    }
    __syncthreads();
#pragma unroll 4
    for (int kk = 0; kk < 32; ++kk) {
      ACC b0 = (ACC)Wl[kk * 128 + colb];
      ACC b1 = (ACC)Wl[kk * 128 + colb + 32];
      ACC b2 = (ACC)Wl[kk * 128 + colb + 64];
      ACC b3 = (ACC)Wl[kk * 128 + colb + 96];
#pragma unroll
      for (int r = 0; r < 8; ++r) {
        ACC a = (ACC)Al[(rg * 8 + r) * 33 + kk];
        acc[r][0] += a * b0; acc[r][1] += a * b1;
        acc[r][2] += a * b2; acc[r][3] += a * b3;
      }
    }
    __syncthreads();
  }
  ACC bb0 = 0, bb1 = 0, bb2 = 0, bb3 = 0;
  if (bias) {
    bb0 = (ACC)bias[colb]; bb1 = (ACC)bias[colb + 32];
    bb2 = (ACC)bias[colb + 64]; bb3 = (ACC)bias[colb + 96];
  }
  for (int r = 0; r < 8; ++r) {
    int row = row0 + rg * 8 + r;
    if (row < n) {
      size_t o = (size_t)row * 128 + colb;
      C[o] = (TC)(acc[r][0] + bb0); C[o + 32] = (TC)(acc[r][1] + bb1);
      C[o + 64] = (TC)(acc[r][2] + bb2); C[o + 96] = (TC)(acc[r][3] + bb3);
    }
  }
}

// matmul with scatter-add output: C[idx[row]] += A[row] @ W (fp32).
__global__ __launch_bounds__(256) void matmul128_sadd(const float* __restrict__ A,
    const float* __restrict__ W, const int* __restrict__ idx,
    float* __restrict__ C, int n) {
  __shared__ float Al[64 * 33];
  __shared__ float Wl[32 * 128];
  int tid = threadIdx.x;
  int colb = tid & 31;
  int rg = tid >> 5;
  int row0 = blockIdx.x * 64;
  float acc[8][4];
#pragma unroll
  for (int r = 0; r < 8; ++r)
#pragma unroll
    for (int j = 0; j < 4; ++j) acc[r][j] = 0.0f;
  for (int kt = 0; kt < 128; kt += 32) {
    for (int i = tid; i < 64 * 32; i += 256) {
      int r = i >> 5, kk = i & 31;
      int row = row0 + r;
      Al[r * 33 + kk] = (row < n) ? A[(size_t)row * 128 + kt + kk] : 0.0f;
    }
    for (int i = tid; i < 32 * 128; i += 256) {
      int kk = i >> 7, c = i & 127;
      Wl[i] = W[(size_t)(kt + kk) * 128 + c];
    }
    __syncthreads();
#pragma unroll 4
    for (int kk = 0; kk < 32; ++kk) {
      float b0 = Wl[kk * 128 + colb];
      float b1 = Wl[kk * 128 + colb + 32];
      float b2 = Wl[kk * 128 + colb + 64];
      float b3 = Wl[kk * 128 + colb + 96];
#pragma unroll
      for (int r = 0; r < 8; ++r) {
        float a = Al[(rg * 8 + r) * 33 + kk];
        acc[r][0] += a * b0; acc[r][1] += a * b1;
        acc[r][2] += a * b2; acc[r][3] += a * b3;
      }
    }
    __syncthreads();
  }
  for (int r = 0; r < 8; ++r) {
    int row = row0 + rg * 8 + r;
    if (row < n) {
      size_t o = (size_t)idx[row] * 128 + colb;
      C[o] += acc[r][0]; C[o + 32] += acc[r][1];
      C[o + 64] += acc[r][2]; C[o + 96] += acc[r][3];
    }
  }
}

// Full-wave float4 agg: 1 wave per node; lanes 0-31 even edges, 32-63 odd.
template <bool RELU>
__global__ __launch_bounds__(256) void agg_conv(const float* __restrict__ hp,
    const int* __restrict__ off, const int* __restrict__ csrc,
    const float* __restrict__ csrw,
    const double* __restrict__ dinv, const double* __restrict__ dgi,
    const float* __restrict__ bias, float* __restrict__ yp, int n) {
  const float4* __restrict__ h = (const float4*)hp;
  float4* __restrict__ y = (float4*)yp;
  int lane = threadIdx.x & 63;
  int c4 = lane & 31;
  int half = lane >> 5;
  int node = blockIdx.x * 4 + (threadIdx.x >> 6);
  if (node >= n) return;
  double di = dinv[node];
  double dg = dgi[node];
  double aX = 0, aY = 0, aZ = 0, aW = 0;
  int p0 = off[node], p1 = off[node + 1];
  int m = p1 - p0;
  int npair = m >> 1;
  int j = 0;
  for (; j + 8 <= npair; j += 8) {
    int e0 = p0 + 2 * j + half;
    int s0 = csrc[e0],      s1 = csrc[e0 + 2],  s2 = csrc[e0 + 4],  s3 = csrc[e0 + 6];
    int s4 = csrc[e0 + 8],  s5 = csrc[e0 + 10], s6 = csrc[e0 + 12], s7 = csrc[e0 + 14];
    double w0 = (double)csrw[e0],      w1 = (double)csrw[e0 + 2];
    double w2 = (double)csrw[e0 + 4],  w3 = (double)csrw[e0 + 6];
    double w4 = (double)csrw[e0 + 8],  w5 = (double)csrw[e0 + 10];
    double w6 = (double)csrw[e0 + 12], w7 = (double)csrw[e0 + 14];
    float4 v0 = h[(size_t)s0 * 32 + c4];
    float4 v1 = h[(size_t)s1 * 32 + c4];
    float4 v2 = h[(size_t)s2 * 32 + c4];
    float4 v3 = h[(size_t)s3 * 32 + c4];
    float4 v4 = h[(size_t)s4 * 32 + c4];
    float4 v5 = h[(size_t)s5 * 32 + c4];
    float4 v6 = h[(size_t)s6 * 32 + c4];
    float4 v7 = h[(size_t)s7 * 32 + c4];
    aX += (double)v0.x * w0; aY += (double)v0.y * w0;
    aZ += (double)v0.z * w0; aW += (double)v0.w * w0;
    aX += (double)v1.x * w1; aY += (double)v1.y * w1;
    aZ += (double)v1.z * w1; aW += (double)v1.w * w1;
    aX += (double)v2.x * w2; aY += (double)v2.y * w2;
    aZ += (double)v2.z * w2; aW += (double)v2.w * w2;
    aX += (double)v3.x * w3; aY += (double)v3.y * w3;
    aZ += (double)v3.z * w3; aW += (double)v3.w * w3;
    aX += (double)v4.x * w4; aY += (double)v4.y * w4;
    aZ += (double)v4.z * w4; aW += (double)v4.w * w4;
    aX += (double)v5.x * w5; aY += (double)v5.y * w5;
    aZ += (double)v5.z * w5; aW += (double)v5.w * w5;
    aX += (double)v6.x * w6; aY += (double)v6.y * w6;
    aZ += (double)v6.z * w6; aW += (double)v6.w * w6;
    aX += (double)v7.x * w7; aY += (double)v7.y * w7;
    aZ += (double)v7.z * w7; aW += (double)v7.w * w7;
  }
  for (; j + 4 <= npair; j += 4) {
    int e0 = p0 + 2 * j + half;
    int s0 = csrc[e0], s1 = csrc[e0 + 2], s2 = csrc[e0 + 4], s3 = csrc[e0 + 6];
    double w0 = (double)csrw[e0],     w1 = (double)csrw[e0 + 2];
    double w2 = (double)csrw[e0 + 4], w3 = (double)csrw[e0 + 6];
    float4 v0 = h[(size_t)s0 * 32 + c4];
    float4 v1 = h[(size_t)s1 * 32 + c4];
    float4 v2 = h[(size_t)s2 * 32 + c4];
    float4 v3 = h[(size_t)s3 * 32 + c4];
    aX += (double)v0.x * w0; aY += (double)v0.y * w0;
    aZ += (double)v0.z * w0; aW += (double)v0.w * w0;
    aX += (double)v1.x * w1; aY += (double)v1.y * w1;
    aZ += (double)v1.z * w1; aW += (double)v1.w * w1;
    aX += (double)v2.x * w2; aY += (double)v2.y * w2;
    aZ += (double)v2.z * w2; aW += (double)v2.w * w2;
    aX += (double)v3.x * w3; aY += (double)v3.y * w3;
    aZ += (double)v3.z * w3; aW += (double)v3.w * w3;
  }
  for (; j < npair; ++j) {
    int e = p0 + 2 * j + half;
    double w = (double)csrw[e];
    float4 v = h[(size_t)csrc[e] * 32 + c4];
    aX += (double)v.x * w; aY += (double)v.y * w;
    aZ += (double)v.z * w; aW += (double)v.w * w;
  }
  if ((m & 1) && half == 0) {
    int e = p1 - 1;
    double w = (double)csrw[e];
    float4 v = h[(size_t)csrc[e] * 32 + c4];
    aX += (double)v.x * w; aY += (double)v.y * w;
    aZ += (double)v.z * w; aW += (double)v.w * w;
  }
  double sX = aX + __shfl_xor(aX, 32);
  double sY = aY + __shfl_xor(aY, 32);
  double sZ = aZ + __shfl_xor(aZ, 32);
  double sW = aW + __shfl_xor(aW, 32);
  if (half == 0) {
    float4 hv = h[(size_t)node * 32 + c4];
    double bx = 0, by = 0, bz = 0, bw = 0;
    if (bias) {
      bx = (double)bias[c4 * 4 + 0]; by = (double)bias[c4 * 4 + 1];
      bz = (double)bias[c4 * 4 + 2]; bw = (double)bias[c4 * 4 + 3];
    }
    double rx = sX * di + (double)hv.x * dg + bx;
    double ry = sY * di + (double)hv.y * dg + by;
    double rz = sZ * di + (double)hv.z * dg + bz;
    double rw = sW * di + (double)hv.w * dg + bw;
    if (RELU) {
      rx = rx > 0.0 ? rx : 0.0; ry = ry > 0.0 ? ry : 0.0;
      rz = rz > 0.0 ? rz : 0.0; rw = rw > 0.0 ? rw : 0.0;
    }
    y[(size_t)node * 32 + c4] = make_float4((float)rx, (float)ry, (float)rz, (float)rw);
  }
}

// level-0 CSR build only
__global__ void count_deg(const int* __restrict__ dst, int m, int* __restrict__ cnt) {
  int e = blockIdx.x * 256 + threadIdx.x;
  if (e < m) atomicAdd(&cnt[dst[e]], 1);
}

__global__ void fin_deg(const int* __restrict__ cnt, double* __restrict__ dinv,
                        double* __restrict__ dgi, int n) {
  int i = blockIdx.x * 256 + threadIdx.x;
  if (i < n) {
    double d = 1.0 + (double)cnt[i];
    dinv[i] = 1.0 / sqrt(d);
    dgi[i] = 1.0 / d;
  }
}

// ---- 2-launch exclusive scan: part(+bsum-scan via ticket) then out ----
__global__ __launch_bounds__(256) void scan_part2(const int* __restrict__ in,
    int* __restrict__ bsum, int n, int* __restrict__ tick) {
  __shared__ int ts[256];
  int base = blockIdx.x * 1024 + threadIdx.x * 4;
  int s = 0;
#pragma unroll
  for (int j = 0; j < 4; ++j) { int i = base + j; if (i < n) s += in[i]; }
  ts[threadIdx.x] = s;
  __syncthreads();
  for (int d = 128; d > 0; d >>= 1) {
    if (threadIdx.x < d) ts[threadIdx.x] += ts[threadIdx.x + d];
    __syncthreads();
  }
  if (threadIdx.x == 0) bsum[blockIdx.x] = ts[0];
  if (!ticket_last(tick)) return;
  // exclusive-scan the nb block sums (nb = gridDim.x <= 256)
  __shared__ int ls[256];
  int t = threadIdx.x;
  int nb = (int)gridDim.x;
  int v = (t < nb) ? bsum[t] : 0;
  ls[t] = v;
  __syncthreads();
  for (int d = 1; d < 256; d <<= 1) {
    int u = (t >= d) ? ls[t - d] : 0;
    __syncthreads();
    ls[t] += u;
    __syncthreads();
  }
  if (t < nb) bsum[t] = ls[t] - v;
}

__global__ __launch_bounds__(256) void scan_out(const int* __restrict__ in,
    const int* __restrict__ bsum, int* __restrict__ out, int n, int nb) {
  __shared__ int ts[256];
  int base = blockIdx.x * 1024 + threadIdx.x * 4;
  int loc[4];
  int s = 0;
#pragma unroll
  for (int j = 0; j < 4; ++j) {
    int i = base + j;
    int v = (i < n) ? in[i] : 0;
    loc[j] = s; s += v;
  }
  ts[threadIdx.x] = s;
  __syncthreads();
  int mine = s;
  for (int d = 1; d < 256; d <<= 1) {
    int u = (threadIdx.x >= d) ? ts[threadIdx.x - d] : 0;
    __syncthreads();
    ts[threadIdx.x] += u;
    __syncthreads();
  }
  int toff = bsum[blockIdx.x] + ts[threadIdx.x] - mine;
#pragma unroll
  for (int j = 0; j < 4; ++j) {
    int i = base + j;
    if (i < n) out[i] = toff + loc[j];
  }
  if (blockIdx.x == nb - 1 && threadIdx.x == 255) out[n] = bsum[blockIdx.x] + ts[255];
}

// ---- dual-scan top-k select: part(+mid via ticket), then out ----
__global__ __launch_bounds__(256) void dsel_part2(const ull* __restrict__ keys,
    const Sel* __restrict__ sel, int2* __restrict__ bsum, int n,
    int* __restrict__ tick) {
  __shared__ int tg[256], te[256];
  ull pref = sel->prefix;
  int base = blockIdx.x * 1024 + threadIdx.x * 4;
  int g = 0, e = 0;
#pragma unroll
  for (int j = 0; j < 4; ++j) {
    int i = base + j;
    if (i < n) {
      ull u = keys[i];
      g += (u > pref) ? 1 : 0;
      e += (u == pref) ? 1 : 0;
    }
  }
  tg[threadIdx.x] = g; te[threadIdx.x] = e;
  __syncthreads();
  for (int d = 128; d > 0; d >>= 1) {
    if (threadIdx.x < d) { tg[threadIdx.x] += tg[threadIdx.x + d]; te[threadIdx.x] += te[threadIdx.x + d]; }
    __syncthreads();
  }
  if (threadIdx.x == 0) bsum[blockIdx.x] = make_int2(tg[0], te[0]);
  if (!ticket_last(tick)) return;
  __shared__ int lg[256], le[256];
  int t = threadIdx.x;
  int nb = (int)gridDim.x;
  int2 v = (t < nb) ? bsum[t] : make_int2(0, 0);
  lg[t] = v.x; le[t] = v.y;
  __syncthreads();
  for (int d = 1; d < 256; d <<= 1) {
    int u1 = (t >= d) ? lg[t - d] : 0;
    int u2 = (t >= d) ? le[t - d] : 0;
    __syncthreads();
    lg[t] += u1; le[t] += u2;
    __syncthreads();
  }
  if (t < nb) bsum[t] = make_int2(lg[t] - v.x, le[t] - v.y);
}

__global__ __launch_bounds__(256) void dsel_out(const ull* __restrict__ keys,
    const Sel* __restrict__ sel, const int2* __restrict__ bsum,
    int* __restrict__ knid, int* __restrict__ idx, int n) {
  __shared__ int tg[256], te[256];
  ull pref = sel->prefix;
  int rem = sel->remaining;
  int base = blockIdx.x * 1024 + threadIdx.x * 4;
  int gflg[4], eflg[4], gloc[4], eloc[4];
  int g = 0, e = 0;
#pragma unroll
  for (int j = 0; j < 4; ++j) {
    int i = base + j;
    int gf = 0, ef = 0;
    if (i < n) {
      ull u = keys[i];
      gf = (u > pref) ? 1 : 0;
      ef = (u == pref) ? 1 : 0;
    }
    gflg[j] = gf; eflg[j] = ef; gloc[j] = g; eloc[j] = e;
    g += gf; e += ef;
  }
  tg[threadIdx.x] = g; te[threadIdx.x] = e;
  __syncthreads();
  int gm = g, em = e;
  for (int d = 1; d < 256; d <<= 1) {
    int u1 = (threadIdx.x >= d) ? tg[threadIdx.x - d] : 0;
    int u2 = (threadIdx.x >= d) ? te[threadIdx.x - d] : 0;
    __syncthreads();
    tg[threadIdx.x] += u1; te[threadIdx.x] += u2;
    __syncthreads();
  }
  int2 bo = bsum[blockIdx.x];
  int goff = bo.x + tg[threadIdx.x] - gm;
  int eoff = bo.y + te[threadIdx.x] - em;
#pragma unroll
  for (int j = 0; j < 4; ++j) {
    int i = base + j;
    if (i < n) {
      int gp = goff + gloc[j];
      int ep = eoff + eloc[j];
      if (gflg[j] || (eflg[j] && ep < rem)) {
        int nid = gp + (ep < rem ? ep : rem);
        knid[i] = nid;
        idx[nid] = i;
      } else {
        knid[i] = -1;
      }
    }
  }
}

__global__ void csr_fill(const int* __restrict__ src, const int* __restrict__ dst,
                         int m, const int* __restrict__ off,
                         int* __restrict__ cursor, int* __restrict__ csrs,
                         float* __restrict__ csrw, const double* __restrict__ dinv) {
  int e = blockIdx.x * 256 + threadIdx.x;
  if (e < m) {
    int d = dst[e];
    int s = src[e];
    int pos = off[d] + atomicAdd(&cursor[d], 1);
    csrs[pos] = s;
    csrw[pos] = (float)dinv[s];
  }
}

// next_deg fused with fin_deg.
__global__ void next_deg_fin(const int* __restrict__ off, const int* __restrict__ csrs,
                             const int* __restrict__ knid, int* __restrict__ ndeg,
                             double* __restrict__ ndinv, double* __restrict__ ndgi,
                             int n) {
  int d = blockIdx.x * 256 + threadIdx.x;
  if (d >= n) return;
  int nd = knid[d];
  if (nd < 0) return;
  int cnt = 0;
  int p1 = off[d + 1];
  for (int p = off[d]; p < p1; ++p) cnt += (knid[csrs[p]] >= 0) ? 1 : 0;
  ndeg[nd] = cnt;
  double dd = 1.0 + (double)cnt;
  ndinv[nd] = 1.0 / sqrt(dd);
  ndgi[nd] = 1.0 / dd;
}

__global__ void next_fill(const int* __restrict__ off, const int* __restrict__ csrs,
                          const int* __restrict__ knid, const int* __restrict__ noff,
                          const double* __restrict__ ndinv,
                          int* __restrict__ ncsrs, float* __restrict__ ncsrw, int n) {
  int d = blockIdx.x * 256 + threadIdx.x;
  if (d >= n) return;
  int nd = knid[d];
  if (nd < 0) return;
  int pos = noff[nd];
  int p1 = off[d + 1];
  for (int p = off[d]; p < p1; ++p) {
    int s = knid[csrs[p]];
    if (s >= 0) { ncsrs[pos] = s; ncsrw[pos] = (float)ndinv[s]; ++pos; }
  }
}

// BN stats (256 blocks, deterministic partials) + bn_final via ticket.
template <typename T>
__global__ __launch_bounds__(256) void bn_stats2(const T* __restrict__ x, int n,
    double* __restrict__ part, const float* __restrict__ g,
    const float* __restrict__ beta, double invn, double* __restrict__ ss,
    int* __restrict__ tick) {
  __shared__ double lsum[256], lsq[256];
  int c = threadIdx.x & 127, half = threadIdx.x >> 7;
  double s = 0, q = 0;
  for (int row = blockIdx.x * 2 + half; row < n; row += 512) {
    double v = (double)x[(size_t)row * 128 + c];
    s += v; q += v * v;
  }
  lsum[threadIdx.x] = s; lsq[threadIdx.x] = q;
  __syncthreads();
  if (half == 0) {
    part[blockIdx.x * 256 + c] = lsum[c] + lsum[c + 128];
    part[blockIdx.x * 256 + 128 + c] = lsq[c] + lsq[c + 128];
  }
  if (!ticket_last(tick)) return;
  int t = threadIdx.x;
  if (t < 128) {
    double ssum = 0, sq = 0;
    for (int b = 0; b < 256; ++b) {
      ssum += part[b * 256 + t];
      sq += part[b * 256 + 128 + t];
    }
    double m = ssum * invn;
    double v = sq * invn - m * m;
    double sc = (double)g[t] / sqrt(v + 1e-5);
    ss[t] = sc;
    ss[128 + t] = (double)beta[t] - m * sc;
  }
}

// BN+ReLU float4, in place (up path).
__global__ void bn_apply_relu4(float4* __restrict__ x, const double* __restrict__ ss,
                               size_t total4) {
  size_t i = (size_t)blockIdx.x * 256 + threadIdx.x;
  if (i < total4) {
    int c0 = (int)((i & 31) * 4);
    float4 v = x[i];
    double r0 = (double)v.x * ss[c0 + 0] + ss[128 + c0 + 0];
    double r1 = (double)v.y * ss[c0 + 1] + ss[128 + c0 + 1];
    double r2 = (double)v.z * ss[c0 + 2] + ss[128 + c0 + 2];
    double r3 = (double)v.w * ss[c0 + 3] + ss[128 + c0 + 3];
    r0 = r0 > 0.0 ? r0 : 0.0; r1 = r1 > 0.0 ? r1 : 0.0;
    r2 = r2 > 0.0 ? r2 : 0.0; r3 = r3 > 0.0 ? r3 : 0.0;
    x[i] = make_float4((float)r0, (float)r1, (float)r2, (float)r3);
  }
}

// Fused (down levels): BN+ReLU -> snap + top-k keys; extra blocks zero hist.
__global__ __launch_bounds__(256) void bn_score_k(const float4* __restrict__ x,
    const double* __restrict__ ss, float4* __restrict__ snap,
    const float* __restrict__ w, ull* __restrict__ keys, int n,
    int nodeBlocks, int* __restrict__ hist, Sel* sel, int k) {
  if ((int)blockIdx.x >= nodeBlocks) {
    int i = (blockIdx.x - nodeBlocks) * 256 + threadIdx.x;
    if (i < 4 * RB) hist[i] = 0;
    if (i == 0) { sel->prefix = 0ULL; sel->remaining = k; }
    return;
  }
  __shared__ double wsh[128];
  __shared__ double wnv;
  int tid = threadIdx.x;
  if (tid < 128) wsh[tid] = (double)w[tid] * (double)w[tid];
  __syncthreads();
  for (int s = 64; s > 0; s >>= 1) {
    if (tid < s) wsh[tid] += wsh[tid + s];
    __syncthreads();
  }
  if (tid == 0) wnv = sqrt(wsh[0]);
  __syncthreads();
  int c4 = tid & 31;
  int node = blockIdx.x * 8 + (tid >> 5);
  if (node >= n) return;
  float4 v = x[(size_t)node * 32 + c4];
  int c0 = c4 * 4;
  double r0 = (double)v.x * ss[c0 + 0] + ss[128 + c0 + 0];
  double r1 = (double)v.y * ss[c0 + 1] + ss[128 + c0 + 1];
  double r2 = (double)v.z * ss[c0 + 2] + ss[128 + c0 + 2];
  double r3 = (double)v.w * ss[c0 + 3] + ss[128 + c0 + 3];
  r0 = r0 > 0.0 ? r0 : 0.0; r1 = r1 > 0.0 ? r1 : 0.0;
  r2 = r2 > 0.0 ? r2 : 0.0; r3 = r3 > 0.0 ? r3 : 0.0;
  float4 o = make_float4((float)r0, (float)r1, (float)r2, (float)r3);
  snap[(size_t)node * 32 + c4] = o;
  double p = (double)o.x * (double)w[c0 + 0] + (double)o.y * (double)w[c0 + 1]
           + (double)o.z * (double)w[c0 + 2] + (double)o.w * (double)w[c0 + 3];
  p += __shfl_xor(p, 1);
  p += __shfl_xor(p, 2);
  p += __shfl_xor(p, 4);
  p += __shfl_xor(p, 8);
  p += __shfl_xor(p, 16);
  if (c4 == 0) {
    double sc = tanh(p / wnv);
    ull u = (ull)__double_as_longlong(sc);
    u = (u >> 63) ? ~u : (u | 0x8000000000000000ULL);
    keys[node] = u;
  }
}

// 16-bit radix pass: hist atomics + (last block, via ticket) boundary pick.
__global__ __launch_bounds__(256) void rs_pass(const ull* __restrict__ keys, int n,
    Sel* sel, int shift, int pass, int* __restrict__ hist, int* __restrict__ tick) {
  int i = blockIdx.x * 256 + threadIdx.x;
  if (i < n) {
    ull k = keys[i];
    bool ok = (pass == 0) || (((k ^ sel->prefix) >> (shift + 16)) == 0);
    if (ok) atomicAdd(&hist[(int)((k >> shift) & 65535)], 1);
  }
  if (!ticket_last(tick)) return;
  // pick among RB bins with 256 threads, 256 bins each
  __shared__ int ls[256];
  int t = threadIdx.x;
  int base = t * 256;
  int own = 0;
  const int4* h4 = (const int4*)hist;
  for (int b = 0; b < 64; ++b) {
    int4 v = h4[t * 64 + b];
    own += v.x + v.y + v.z + v.w;
  }
  ls[t] = own;
  __syncthreads();
  for (int d = 1; d < 256; d <<= 1) {
    int v = (t + d < 256) ? ls[t + d] : 0;
    __syncthreads();
    ls[t] += v;
    __syncthreads();
  }
  int rem = sel->remaining;
  int St = ls[t];
  int Snext = St - own;
  if (Snext < rem && rem <= St) {
    int cum = Snext;
    for (int b = 255; b >= 0; --b) {
      int c = hist[base + b];
      if (cum + c >= rem) {
        sel->prefix |= ((ull)(base + b)) << shift;
        sel->remaining = rem - cum;
        break;
      }
      cum += c;
    }
  }
}

__global__ void gather_rows4(const float4* __restrict__ xs, const int* __restrict__ idx,
                             float4* __restrict__ xo, int k) {
  int i = blockIdx.x * 256 + threadIdx.x;
  if (i < k * 32) xo[i] = xs[(size_t)idx[i >> 5] * 32 + (i & 31)];
}

// ---------------- host ----------------

extern "C" void kernel_launch(void* const* d_in, const int* in_sizes, int n_in,
                              void* d_out, int out_size, void* d_ws, size_t ws_size,
                              hipStream_t stream) {
  (void)in_sizes; (void)out_size;
  if (n_in < 17) return;
  const float* x_in   = (const float*)d_in[0];
  const int*   ei     = (const int*)  d_in[1];
  const float* in_W   = (const float*)d_in[2];
  const float* in_b   = (const float*)d_in[3];
  const float* dn_W   = (const float*)d_in[4];
  const float* dn_b   = (const float*)d_in[5];
  const float* dn_g   = (const float*)d_in[6];
  const float* dn_bt  = (const float*)d_in[7];
  const float* pool_w = (const float*)d_in[8];
  const float* bot_W  = (const float*)d_in[9];
  const float* bot_b  = (const float*)d_in[10];
  const float* up_W   = (const float*)d_in[11];
  const float* up_b   = (const float*)d_in[12];
  const float* up_g   = (const float*)d_in[13];
  const float* up_bt  = (const float*)d_in[14];
  const float* out_W  = (const float*)d_in[15];
  const float* out_b  = (const float*)d_in[16];
  float* outp = (float*)d_out;

  char* base = (char*)d_ws;
  size_t off = 0;
  auto alloc = [&](size_t b) -> void* {
    void* r = base + off;
    off = (off + b + 255) & ~(size_t)255;
    return r;
  };
  float* bufA = (float*)alloc((size_t)N0_ * 128 * 4);
  float* bufB = (float*)alloc((size_t)N0_ * 128 * 4);
  float* xs0f = (float*)alloc((size_t)N0_ * 128 * 4);
  float* xs1f = (float*)alloc((size_t)N1_ * 128 * 4);
  float* xs2f = (float*)alloc((size_t)N2_ * 128 * 4);

  int* csrs0 = (int*)alloc((size_t)EDG * 4);
  int* csrs1 = (int*)alloc((size_t)CAP1 * 4);
  int* csrs2 = (int*)alloc((size_t)CAP2 * 4);
  int* csrs3 = (int*)alloc((size_t)CAP3 * 4);
  float* csrw0 = (float*)alloc((size_t)EDG * 4);
  float* csrw1 = (float*)alloc((size_t)CAP1 * 4);
  float* csrw2 = (float*)alloc((size_t)CAP2 * 4);
  float* csrw3 = (float*)alloc((size_t)CAP3 * 4);
  int* csro0 = (int*)alloc((size_t)(N0_ + 1) * 4);
  int* csro1 = (int*)alloc((size_t)(N1_ + 1) * 4);
  int* csro2 = (int*)alloc((size_t)(N2_ + 1) * 4);
  int* csro3 = (int*)alloc((size_t)(N3_ + 1) * 4);
  double* dinv0 = (double*)alloc((size_t)N0_ * 8); double* dgi0 = (double*)alloc((size_t)N0_ * 8);
  double* dinv1 = (double*)alloc((size_t)N1_ * 8); double* dgi1 = (double*)alloc((size_t)N1_ * 8);
  double* dinv2 = (double*)alloc((size_t)N2_ * 8); double* dgi2 = (double*)alloc((size_t)N2_ * 8);
  double* dinv3 = (double*)alloc((size_t)N3_ * 8); double* dgi3 = (double*)alloc((size_t)N3_ * 8);
  ull* keys = (ull*)alloc((size_t)N0_ * 8);
  int* knid  = (int*)alloc((size_t)N0_ * 4);
  int* degcnt = (int*)alloc((size_t)N0_ * 4);
  int* cursor = (int*)alloc((size_t)N0_ * 4);
  int* idx0 = (int*)alloc((size_t)N1_ * 4);
  int* idx1 = (int*)alloc((size_t)N2_ * 4);
  int* idx2 = (int*)alloc((size_t)N3_ * 4);
  int* hist = (int*)alloc((size_t)4 * RB * 4);     // 1 MB: 4 passes x 64K bins
  Sel* sel  = (Sel*)alloc(256);
  int* bscan = (int*)alloc(256 * 8);
  double* bns = (double*)alloc((size_t)256 * 256 * 8);
  double* ssb = (double*)alloc(256 * 8);
  int* tick = (int*)alloc(32 * 4);                 // ticket slots
  if (off > ws_size) {
    sentinel_k<<<1, 64, 0, stream>>>(outp, (float)ws_size);
    return;
  }

  const int nL[4]   = {N0_, N1_, N2_, N3_};
  int* csrsL[4] = {csrs0, csrs1, csrs2, csrs3};
  float* csrwL[4] = {csrw0, csrw1, csrw2, csrw3};
  int* csroL[4] = {csro0, csro1, csro2, csro3};
  double* dinvL[4] = {dinv0, dinv1, dinv2, dinv3};
  double* dgiL[4]  = {dgi0, dgi1, dgi2, dgi3};
  int* idxL[3] = {idx0, idx1, idx2};

  auto cdiv = [](int a, int b) { return (a + b - 1) / b; };

  hipMemsetAsync(tick, 0, 32 * 4, stream);

  // slot map: 0 csr0-scan; 1+i pool-scan; 4+i bn-down; 7+u bn-up;
  //           10+i*4+p rs; 22+i dsel
  auto scan = [&](const int* in, int* out, int n, int slot) {
    int nb = cdiv(n, 1024);
    scan_part2<<<nb, 256, 0, stream>>>(in, bscan, n, tick + slot);
    scan_out<<<nb, 256, 0, stream>>>(in, bscan, out, n, nb);
  };

  auto bn_core = [&](float* xp, int n, const float* g, const float* b, int slot) {
    bn_stats2<float><<<256, 256, 0, stream>>>(xp, n, bns, g, b, 1.0 / (double)n,
                                              ssb, tick + slot);
  };

  auto pool = [&](int i, const float* xcur, float* xnext) {
    int n = nL[i], k = nL[i + 1];
    int nb = cdiv(n, 1024);
    for (int p = 0; p < 4; ++p) {
      int shift = 48 - 16 * p;
      rs_pass<<<cdiv(n, 256), 256, 0, stream>>>(keys, n, sel, shift, p,
                                                hist + p * RB, tick + 10 + i * 4 + p);
    }
    dsel_part2<<<nb, 256, 0, stream>>>(keys, sel, (int2*)bscan, n, tick + 22 + i);
    dsel_out<<<nb, 256, 0, stream>>>(keys, sel, (const int2*)bscan, knid, idxL[i], n);
    gather_rows4<<<cdiv(k * 32, 256), 256, 0, stream>>>(
        (const float4*)xcur, idxL[i], (float4*)xnext, k);
    next_deg_fin<<<cdiv(n, 256), 256, 0, stream>>>(csroL[i], csrsL[i], knid, degcnt,
                                                   dinvL[i + 1], dgiL[i + 1], n);
    scan(degcnt, csroL[i + 1], k, 1 + i);
    next_fill<<<cdiv(n, 256), 256, 0, stream>>>(csroL[i], csrsL[i], knid,
        csroL[i + 1], dinvL[i + 1], csrsL[i + 1], csrwL[i + 1], n);
  };

  // ---- level 0 CSR (from raw edge list) ----
  hipMemsetAsync(degcnt, 0, (size_t)N0_ * 4, stream);
  count_deg<<<cdiv(EDG, 256), 256, 0, stream>>>(ei + EDG, EDG, degcnt);
  fin_deg<<<cdiv(N0_, 256), 256, 0, stream>>>(degcnt, dinv0, dgi0, N0_);
  scan(degcnt, csro0, N0_, 0);
  hipMemsetAsync(cursor, 0, (size_t)N0_ * 4, stream);
  csr_fill<<<cdiv(EDG, 256), 256, 0, stream>>>(ei, ei + EDG, EDG, csro0, cursor,
                                               csrs0, csrw0, dinv0);

  // ---- initial conv (agg-first) ----
  agg_conv<false><<<cdiv(N0_, 4), 256, 0, stream>>>(
      x_in, csro0, csrs0, csrw0, dinv0, dgi0, nullptr, bufB, N0_);
  matmul128<float, float, double><<<cdiv(N0_, 64), 256, 0, stream>>>(bufB, in_W, in_b, bufA, N0_);

  // ---- down level 0 ----
  matmul128<float, float, double><<<cdiv(N0_, 64), 256, 0, stream>>>(bufA, dn_W, nullptr, bufB, N0_);
  agg_conv<false><<<cdiv(N0_, 4), 256, 0, stream>>>(
      bufB, csro0, csrs0, csrw0, dinv0, dgi0, dn_b, bufA, N0_);
  bn_core(bufA, N0_, dn_g, dn_bt, 4);
  {
    int nodeBlocks = cdiv(N0_, 8);
    bn_score_k<<<nodeBlocks + 1024, 256, 0, stream>>>(
        (const float4*)bufA, ssb, (float4*)xs0f, pool_w, keys, N0_, nodeBlocks,
        hist, sel, N1_);
  }
  pool(0, xs0f, bufB);

  // ---- down level 1 ----
  matmul128<float, float, double><<<cdiv(N1_, 64), 256, 0, stream>>>(bufB, dn_W + 16384, nullptr, bufA, N1_);
  agg_conv<false><<<cdiv(N1_, 4), 256, 0, stream>>>(
      bufA, csro1, csrs1, csrw1, dinv1, dgi1, dn_b + 128, bufB, N1_);
  bn_core(bufB, N1_, dn_g + 128, dn_bt + 128, 5);
  {
    int nodeBlocks = cdiv(N1_, 8);
    bn_score_k<<<nodeBlocks + 1024, 256, 0, stream>>>(
        (const float4*)bufB, ssb, (float4*)xs1f, pool_w + 128, keys, N1_, nodeBlocks,
        hist, sel, N2_);
  }
  pool(1, xs1f, bufA);

  // ---- down level 2 ----
  matmul128<float, float, double><<<cdiv(N2_, 64), 256, 0, stream>>>(bufA, dn_W + 32768, nullptr, bufB, N2_);
  agg_conv<false><<<cdiv(N2_, 4), 256, 0, stream>>>(
      bufB, csro2, csrs2, csrw2, dinv2, dgi2, dn_b + 256, bufA, N2_);
  bn_core(bufA, N2_, dn_g + 256, dn_bt + 256, 6);
  {
    int nodeBlocks = cdiv(N2_, 8);
    bn_score_k<<<nodeBlocks + 1024, 256, 0, stream>>>(
        (const float4*)bufA, ssb, (float4*)xs2f, pool_w + 256, keys, N2_, nodeBlocks,
        hist, sel, N3_);
  }
  pool(2, xs2f, bufB);

  // ---- bottom: x3 in B, h3 -> A, z3 (relu) -> B ----
  matmul128<float, float, double><<<cdiv(N3_, 64), 256, 0, stream>>>(bufB, bot_W, nullptr, bufA, N3_);
  float* zf = bufB;
  float* hf = bufA;
  agg_conv<true><<<cdiv(N3_, 4), 256, 0, stream>>>(
      bufA, csro3, csrs3, csrw3, dinv3, dgi3, bot_b, zf, N3_);

  // ---- up path: z in B, hf in A; scatter-add fused into the z matmul ----
  for (int u = 0; u < 3; ++u) {
    int l = 2 - u;
    int nl = nL[l], nz = nL[l + 1];
    const float* Wt = up_W + u * 32768;
    const float* Wb = up_W + u * 32768 + 16384;
    const float* xsf = (u == 0) ? xs2f : (u == 1) ? xs1f : xs0f;
    matmul128<float, float, float><<<cdiv(nl, 64), 256, 0, stream>>>(xsf, Wb, nullptr, hf, nl);
    matmul128_sadd<<<cdiv(nz, 64), 256, 0, stream>>>(zf, Wt, idxL[l], hf, nz);
    agg_conv<false><<<cdiv(nl, 4), 256, 0, stream>>>(
        hf, csroL[l], csrsL[l], csrwL[l], dinvL[l], dgiL[l], up_b + u * 128, zf, nl);
    bn_core(zf, nl, up_g + u * 128, up_bt + u * 128, 7 + u);
    bn_apply_relu4<<<cdiv(nl * 32, 256), 256, 0, stream>>>(
        (float4*)zf, ssb, (size_t)nl * 32);
  }

  // ---- final conv -> d_out ----
  matmul128<float, float, float><<<cdiv(N0_, 64), 256, 0, stream>>>(zf, out_W, nullptr, hf, N0_);
  agg_conv<false><<<cdiv(N0_, 4), 256, 0, stream>>>(
      hf, csro0, csrs0, csrw0, dinv0, dgi0, out_b, outp, N0_);
}